// Round 3
// baseline (706.296 us; speedup 1.0000x reference)
//
#include <hip/hip_runtime.h>
#include <hip/hip_bf16.h>
#include <stdint.h>

#define NN 100000
#define NE 1600000
#define HD 128
#define NG 500
#define NPG 200

typedef __attribute__((ext_vector_type(8))) short short8v;
typedef __attribute__((ext_vector_type(4))) float float4v;

// ---------- bf16 helpers (bit-level, RNE) ----------
__device__ __forceinline__ float bflo(unsigned int u) { return __uint_as_float(u << 16); }
__device__ __forceinline__ float bfhi(unsigned int u) { return __uint_as_float(u & 0xffff0000u); }
__device__ __forceinline__ unsigned int packbf(float a, float b) {
  unsigned int ua = __float_as_uint(a), ub = __float_as_uint(b);
  ua += 0x7fffu + ((ua >> 16) & 1u);
  ub += 0x7fffu + ((ub >> 16) & 1u);
  return (ua >> 16) | (ub & 0xffff0000u);
}

// ---------- edge dtype helper (int32 vs int64 detected at runtime) ----------
__device__ __forceinline__ int edge_at(const void* p, int is64, int idx) {
  return is64 ? (int)((const long long*)p)[idx] : ((const int*)p)[idx];
}

__global__ void k_detect(const void* __restrict__ edges, int* __restrict__ flag) {
  if (threadIdx.x == 0 && blockIdx.x == 0) {
    const unsigned int* p = (const unsigned int*)edges;
    unsigned int odd = 0u, even = 0u;
    for (int i = 0; i < 256; ++i) { even |= p[2 * i]; odd |= p[2 * i + 1]; }
    flag[0] = (odd == 0u && even != 0u) ? 1 : 0;  // all-odd-zero => int64
  }
}

// ---------- pass A: count degrees + scatter packed edge into dst-bucket ----------
// bucket b covers nodes [128b,128b+128); record = (dst&127)<<17 | src  (src<2^17)
__global__ void k_passA(const void* __restrict__ edges, const int* __restrict__ flag,
                        int* __restrict__ cnt, int* __restrict__ bfill,
                        unsigned int* __restrict__ bucket) {
  int e = blockIdx.x * blockDim.x + threadIdx.x;
  if (e >= NE) return;
  int f = flag[0];
  int s = edge_at(edges, f, e);
  int d = edge_at(edges, f, NE + e);
  atomicAdd(&cnt[d], 1);
  int b = d >> 7;
  int pos = atomicAdd(&bfill[b], 1);
  bucket[(size_t)b * 4096 + pos] = ((unsigned)(d & 127) << 17) | (unsigned)s;
}

__global__ void k_dinv(const int* __restrict__ cnt, float* __restrict__ dinv) {
  int i = blockIdx.x * blockDim.x + threadIdx.x;
  if (i < NN) dinv[i] = rsqrtf((float)(cnt[i] + 1));  // +1 self loop
}

// ---------- exclusive scan of cnt -> rowstart ----------
__global__ void k_scan_block(const int* __restrict__ cnt, int* __restrict__ rowstart,
                             int* __restrict__ bsums) {
  __shared__ int s[256];
  int tid = threadIdx.x;
  int i = blockIdx.x * 256 + tid;
  int v = (i < NN) ? cnt[i] : 0;
  s[tid] = v;
  __syncthreads();
  for (int off = 1; off < 256; off <<= 1) {
    int t = (tid >= off) ? s[tid - off] : 0;
    __syncthreads();
    s[tid] += t;
    __syncthreads();
  }
  if (i < NN) rowstart[i] = s[tid] - v;
  if (tid == 255) bsums[blockIdx.x] = s[255];
}

__global__ void k_scan_sums(int* __restrict__ bsums, int nb) {
  __shared__ int s[512];
  int tid = threadIdx.x;
  int v = (tid < nb) ? bsums[tid] : 0;
  s[tid] = v;
  __syncthreads();
  for (int off = 1; off < 512; off <<= 1) {
    int t = (tid >= off) ? s[tid - off] : 0;
    __syncthreads();
    s[tid] += t;
    __syncthreads();
  }
  if (tid < nb) bsums[tid] = s[tid] - v;
}

__global__ void k_scan_add(int* __restrict__ rowstart, const int* __restrict__ bsums) {
  int i = blockIdx.x * blockDim.x + threadIdx.x;
  if (i < NN) rowstart[i] += bsums[i >> 8];
  if (i == 0) rowstart[NN] = NE;
}

// ---------- pass B: bucket -> CSR (src only, 4B), staged in LDS ----------
__global__ __launch_bounds__(256) void k_passB(const unsigned int* __restrict__ bucket,
                                               const int* __restrict__ bfill,
                                               const int* __restrict__ rowstart,
                                               int* __restrict__ csr) {
  __shared__ int fill[128];
  __shared__ int rs[129];
  __shared__ int stage[4096];
  int b = blockIdx.x, tid = threadIdx.x;
  int nbase = b << 7;
  int nn = NN - nbase;
  if (nn > 128) nn = 128;
  if (tid <= nn) rs[tid] = rowstart[nbase + tid];
  if (tid < 128) fill[tid] = 0;
  __syncthreads();
  int base = rs[0];
  int ne = bfill[b];
  for (int i = tid; i < ne; i += 256) {
    unsigned int v = bucket[(size_t)b * 4096 + i];
    int src = (int)(v & 0x1FFFFu);
    int ld = (int)(v >> 17);
    int pos = atomicAdd(&fill[ld], 1);
    stage[rs[ld] - base + pos] = src;
  }
  __syncthreads();
  for (int i = tid; i < ne; i += 256) csr[base + i] = stage[i];
}

// ---------- fp32 -> bf16 convert with dinv pre-scale: xs[v] = dinv[v]*x[v] ----------
__global__ void k_cvt2(const float4* __restrict__ in, uint4* __restrict__ out,
                       const float* __restrict__ dinv) {
  int i = blockIdx.x * 256 + threadIdx.x;  // 8-element group; node = i>>4
  float dv = dinv[i >> 4];
  float4 a = in[(size_t)i * 2], b = in[(size_t)i * 2 + 1];
  uint4 o;
  o.x = packbf(a.x * dv, a.y * dv); o.y = packbf(a.z * dv, a.w * dv);
  o.z = packbf(b.x * dv, b.y * dv); o.w = packbf(b.z * dv, b.w * dv);
  out[i] = o;
}

// ---------- gather-aggregate core: acc = self + sum_src rows (pure adds) ----------
__device__ __forceinline__ void acc8(float* a, uint4 v) {
  a[0] += bflo(v.x); a[1] += bfhi(v.x); a[2] += bflo(v.y); a[3] += bfhi(v.y);
  a[4] += bflo(v.z); a[5] += bfhi(v.z); a[6] += bflo(v.w); a[7] += bfhi(v.w);
}

#define AGG_CORE(IN, NODE, L, A)                                                 \
  float A[8];                                                                    \
  {                                                                              \
    uint4 sv = IN[(size_t)(NODE)*16 + (L)];                                      \
    A[0] = bflo(sv.x); A[1] = bfhi(sv.x); A[2] = bflo(sv.y); A[3] = bfhi(sv.y);  \
    A[4] = bflo(sv.z); A[5] = bfhi(sv.z); A[6] = bflo(sv.w); A[7] = bfhi(sv.w);  \
  }                                                                              \
  {                                                                              \
    int i = rowstart[NODE], end = rowstart[(NODE) + 1];                          \
    for (; i + 3 < end; i += 4) {                                                \
      int s0 = csr[i], s1 = csr[i + 1], s2 = csr[i + 2], s3 = csr[i + 3];        \
      uint4 v0 = IN[(size_t)s0 * 16 + (L)];                                      \
      uint4 v1 = IN[(size_t)s1 * 16 + (L)];                                      \
      uint4 v2 = IN[(size_t)s2 * 16 + (L)];                                      \
      uint4 v3 = IN[(size_t)s3 * 16 + (L)];                                      \
      acc8(A, v0); acc8(A, v1); acc8(A, v2); acc8(A, v3);                        \
    }                                                                            \
    for (; i < end; ++i) {                                                       \
      uint4 v0 = IN[(size_t)csr[i] * 16 + (L)];                                  \
      acc8(A, v0);                                                               \
    }                                                                            \
  }

// agg1: aggb[v] = bf16( dinv[v] * (xs[v] + sum xs[src]) )   [= Agg(x)[v]]
__global__ __launch_bounds__(256) void k_agg1(const uint4* __restrict__ in,
                                              uint4* __restrict__ out,
                                              const int* __restrict__ rowstart,
                                              const int* __restrict__ csr,
                                              const float* __restrict__ dinv) {
  int node = blockIdx.x * 16 + (threadIdx.x >> 4);
  int l = threadIdx.x & 15;
  AGG_CORE(in, node, l, a)
  float dv = dinv[node];
  uint4 o;
  o.x = packbf(a[0] * dv, a[1] * dv); o.y = packbf(a[2] * dv, a[3] * dv);
  o.z = packbf(a[4] * dv, a[5] * dv); o.w = packbf(a[6] * dv, a[7] * dv);
  out[(size_t)node * 16 + l] = o;
}

// agg2 + fused per-graph sum pool (16 nodes/block; block may span 2 graphs)
__global__ __launch_bounds__(256) void k_agg2p(const uint4* __restrict__ in,
                                               float* __restrict__ poolsum,
                                               const int* __restrict__ rowstart,
                                               const int* __restrict__ csr,
                                               const float* __restrict__ dinv) {
  __shared__ float sh[16][128];
  int nl = threadIdx.x >> 4, l = threadIdx.x & 15;
  int node = blockIdx.x * 16 + nl;
  AGG_CORE(in, node, l, a)
  float dv = dinv[node];
#pragma unroll
  for (int j = 0; j < 8; ++j) a[j] *= dv;
  *(float4*)&sh[nl][l * 8] = make_float4(a[0], a[1], a[2], a[3]);
  *(float4*)&sh[nl][l * 8 + 4] = make_float4(a[4], a[5], a[6], a[7]);
  __syncthreads();
  int tid = threadIdx.x;
  if (tid < 128) {
    int n0 = blockIdx.x * 16;
    int gA = n0 / 200;
    int split = (gA + 1) * 200 - n0;  // nodes [0,split) belong to gA
    if (split > 16) split = 16;
    float sA = 0.f, sB = 0.f;
#pragma unroll
    for (int n = 0; n < 16; ++n) {
      float v = sh[n][tid];
      if (n < split) sA += v; else sB += v;
    }
    atomicAdd(&poolsum[gA * 128 + tid], sA);
    if (split < 16) atomicAdd(&poolsum[(gA + 1) * 128 + tid], sB);
  }
}

// ---------- GEMM1 (MFMA bf16): h1s = bf16( dinv[r] * relu(A @ W1 + b1) ) ----------
// A bf16 [M][128] from global; W fp32 [128][128] -> bf16 transposed+swizzled in LDS.
__global__ __launch_bounds__(256) void k_gemm1m(const unsigned short* __restrict__ A,
                                                const float* __restrict__ W,
                                                const float* __restrict__ bias,
                                                const float* __restrict__ dinv,
                                                unsigned short* __restrict__ out, int M) {
  __shared__ unsigned short Wt[128 * 128];  // byte addr: c*256 + ((2k) ^ ((c&7)<<4))
  int tid = threadIdx.x;
  for (int i = tid; i < 8192; i += 256) {
    int c = i >> 6, kp = i & 63, k = kp * 2;
    float w0 = W[(size_t)k * 128 + c];
    float w1 = W[(size_t)(k + 1) * 128 + c];
    int off = (k * 2) ^ ((c & 7) << 4);
    *(unsigned int*)((char*)Wt + c * 256 + off) = packbf(w0, w1);
  }
  __syncthreads();

  int w = tid >> 6, lane = tid & 63;
  int m = lane & 15, g = lane >> 4;
  int row0 = blockIdx.x * 128 + w * 32;

  // A-fragments straight from global: lane holds A[row=m][k=g*8+j], per rt/ks
  short8v afr[2][4];
#pragma unroll
  for (int rt = 0; rt < 2; ++rt) {
    int r = row0 + rt * 16 + m;
    bool ok = r < M;
    const unsigned short* ap = A + (size_t)r * 128 + g * 8;
#pragma unroll
    for (int ks = 0; ks < 4; ++ks) {
      short8v z;
#pragma unroll
      for (int j = 0; j < 8; ++j) z[j] = 0;
      afr[rt][ks] = ok ? *(const short8v*)(ap + ks * 32) : z;
    }
  }

  float4v acc[2][8];
#pragma unroll
  for (int rt = 0; rt < 2; ++rt)
#pragma unroll
    for (int ct = 0; ct < 8; ++ct) acc[rt][ct] = (float4v)0.f;

#pragma unroll
  for (int ks = 0; ks < 4; ++ks) {
    short8v bfr[8];
#pragma unroll
    for (int ct = 0; ct < 8; ++ct) {
      int c = ct * 16 + m;
      int off = (ks * 64 + g * 16) ^ ((c & 7) << 4);
      bfr[ct] = *(const short8v*)((const char*)Wt + c * 256 + off);
    }
#pragma unroll
    for (int rt = 0; rt < 2; ++rt)
#pragma unroll
      for (int ct = 0; ct < 8; ++ct)
        acc[rt][ct] = __builtin_amdgcn_mfma_f32_16x16x32_bf16(afr[rt][ks], bfr[ct],
                                                              acc[rt][ct], 0, 0, 0);
  }

  // D: col = lane&15 (+16ct), row = g*4 + reg (+16rt)
#pragma unroll
  for (int rt = 0; rt < 2; ++rt) {
#pragma unroll
    for (int j = 0; j < 4; ++j) {
      int r = row0 + rt * 16 + g * 4 + j;
      if (r >= M) continue;
      float dv = dinv[r];
#pragma unroll
      for (int ct = 0; ct < 8; ++ct) {
        int c = ct * 16 + m;
        float v = fmaxf(acc[rt][ct][j] + bias[c], 0.f) * dv;
        out[(size_t)r * 128 + c] = (unsigned short)(packbf(v, 0.f) & 0xFFFFu);
      }
    }
  }
}

// ---------- GEMM2: fp32 A (scaled) @ fp32 W -> fp32 out ----------
__global__ __launch_bounds__(256) void k_gemm2(const float* __restrict__ A,
                                               const float* __restrict__ W,
                                               const float* __restrict__ bias,
                                               float* __restrict__ out, int M, float ascale) {
  __shared__ float Xs[32 * 132];
  __shared__ float Ws[32 * 128];
  const int tid = threadIdx.x;
  const int row0 = blockIdx.x * 128;
  const int rg = tid >> 4, cg = tid & 15;
  const int r0 = rg * 8, c0 = cg * 8;

  float bl[8];
#pragma unroll
  for (int j = 0; j < 8; ++j) bl[j] = bias[c0 + j];

  float acc[8][8];
#pragma unroll
  for (int i = 0; i < 8; ++i)
#pragma unroll
    for (int j = 0; j < 8; ++j) acc[i][j] = 0.f;

  for (int kt = 0; kt < 128; kt += 32) {
    __syncthreads();
#pragma unroll
    for (int i = tid; i < 1024; i += 256) {
      int r = i >> 3, c4 = i & 7;
      float4 v = make_float4(0.f, 0.f, 0.f, 0.f);
      if (row0 + r < M) v = *(const float4*)&A[(size_t)(row0 + r) * 128 + kt + c4 * 4];
      Xs[(c4 * 4 + 0) * 132 + r] = v.x * ascale;
      Xs[(c4 * 4 + 1) * 132 + r] = v.y * ascale;
      Xs[(c4 * 4 + 2) * 132 + r] = v.z * ascale;
      Xs[(c4 * 4 + 3) * 132 + r] = v.w * ascale;
    }
#pragma unroll
    for (int i = tid; i < 1024; i += 256) {
      int k = i >> 5, c4 = i & 31;
      *(float4*)&Ws[k * 128 + c4 * 4] = *(const float4*)&W[(size_t)(kt + k) * 128 + c4 * 4];
    }
    __syncthreads();
#pragma unroll 8
    for (int k = 0; k < 32; ++k) {
      float4 x0 = *(const float4*)&Xs[k * 132 + r0];
      float4 x1 = *(const float4*)&Xs[k * 132 + r0 + 4];
      float4 w0 = *(const float4*)&Ws[k * 128 + c0];
      float4 w1 = *(const float4*)&Ws[k * 128 + c0 + 4];
      float xr[8] = {x0.x, x0.y, x0.z, x0.w, x1.x, x1.y, x1.z, x1.w};
      float wr[8] = {w0.x, w0.y, w0.z, w0.w, w1.x, w1.y, w1.z, w1.w};
#pragma unroll
      for (int i = 0; i < 8; ++i)
#pragma unroll
        for (int j = 0; j < 8; ++j) acc[i][j] = fmaf(xr[i], wr[j], acc[i][j]);
    }
  }

#pragma unroll
  for (int i = 0; i < 8; ++i) {
    int r = row0 + r0 + i;
    if (r < M) {
      float o[8];
#pragma unroll
      for (int j = 0; j < 8; ++j) o[j] = acc[i][j] + bl[j];
      *(float4*)&out[(size_t)r * 128 + c0] = make_float4(o[0], o[1], o[2], o[3]);
      *(float4*)&out[(size_t)r * 128 + c0 + 4] = make_float4(o[4], o[5], o[6], o[7]);
    }
  }
}

extern "C" void kernel_launch(void* const* d_in, const int* in_sizes, int n_in,
                              void* d_out, int out_size, void* d_ws, size_t ws_size,
                              hipStream_t stream) {
  const float* x  = (const float*)d_in[0];
  const void* edges = d_in[1];
  const float* W1 = (const float*)d_in[3];
  const float* b1 = (const float*)d_in[4];
  const float* W2 = (const float*)d_in[5];
  const float* b2 = (const float*)d_in[6];
  float* out = (float*)d_out;

  // workspace layout (bytes), ~97.5 MB total
  char* ws = (char*)d_ws;
  int*   cnt      = (int*)(ws + 0);            // 400000  } zeroed
  int*   bfill    = (int*)(ws + 400000);       // 4096    } zeroed
  float* poolsum  = (float*)(ws + 404096);     // 256000  } zeroed
  int*   rowstart = (int*)(ws + 660096);       // 400016
  int*   bsums    = (int*)(ws + 1060112);      // 2048
  float* dinv     = (float*)(ws + 1062160);    // 400000
  int*   flag     = (int*)(ws + 1462160);      // 16
  unsigned int* bucket = (unsigned int*)(ws + 1462176);  // 12.8 MB (782*4096*4)
  int*   csr      = (int*)(ws + 14274464);     // 6.4 MB
  void*  xs       = (void*)(ws + 20674464);    // 25.6 MB  bf16 dinv*x
  void*  aggb     = (void*)(ws + 46274464);    // 25.6 MB  bf16 Agg(x)
  void*  h1s      = (void*)(ws + 71874464);    // 25.6 MB  bf16 dinv*h1

  hipMemsetAsync(ws, 0, 660096, stream);  // cnt + bfill + poolsum

  k_detect<<<1, 64, 0, stream>>>(edges, flag);
  k_passA<<<(NE + 255) / 256, 256, 0, stream>>>(edges, flag, cnt, bfill, bucket);
  k_dinv<<<(NN + 255) / 256, 256, 0, stream>>>(cnt, dinv);
  k_scan_block<<<391, 256, 0, stream>>>(cnt, rowstart, bsums);
  k_scan_sums<<<1, 512, 0, stream>>>(bsums, 391);
  k_scan_add<<<391, 256, 0, stream>>>(rowstart, bsums);
  k_passB<<<782, 256, 0, stream>>>(bucket, bfill, rowstart, csr);

  // xs = bf16(dinv * x)
  k_cvt2<<<NN * HD / 8 / 256, 256, 0, stream>>>((const float4*)x, (uint4*)xs, dinv);

  // conv1: aggb = dinv*(xs self+gather) = Agg(x); h1s = dinv*relu(aggb@W1+b1)
  k_agg1<<<NN / 16, 256, 0, stream>>>((const uint4*)xs, (uint4*)aggb, rowstart, csr, dinv);
  k_gemm1m<<<(NN + 127) / 128, 256, 0, stream>>>((const unsigned short*)aggb, W1, b1, dinv,
                                                 (unsigned short*)h1s, NN);
  // conv2 fused with pool: poolsum = sum_graph( dinv*(h1s self+gather) )
  k_agg2p<<<NN / 16, 256, 0, stream>>>((const uint4*)h1s, poolsum, rowstart, csr, dinv);
  k_gemm2<<<(NG + 127) / 128, 256, 0, stream>>>(poolsum, W2, b2, out, NG, 1.f / (float)NPG);
}

// Round 4
// 317.772 us; speedup vs baseline: 2.2226x; 2.2226x over previous
//
#include <hip/hip_runtime.h>
#include <hip/hip_bf16.h>
#include <stdint.h>

#define NN 100000
#define NE 1600000
#define HD 128
#define NG 500
#define NPG 200

#define NBK 782      // node buckets of 128: ceil(NN/128)
#define NBLK 128     // scatter blocks
#define CHUNK 12500  // edges per scatter block (NBLK*CHUNK == NE)

typedef __attribute__((ext_vector_type(8))) short short8v;
typedef __attribute__((ext_vector_type(4))) float float4v;

// ---------- bf16 helpers (bit-level, RNE) ----------
__device__ __forceinline__ float bflo(unsigned int u) { return __uint_as_float(u << 16); }
__device__ __forceinline__ float bfhi(unsigned int u) { return __uint_as_float(u & 0xffff0000u); }
__device__ __forceinline__ unsigned int packbf(float a, float b) {
  unsigned int ua = __float_as_uint(a), ub = __float_as_uint(b);
  ua += 0x7fffu + ((ua >> 16) & 1u);
  ub += 0x7fffu + ((ub >> 16) & 1u);
  return (ua >> 16) | (ub & 0xffff0000u);
}

// ---------- edge dtype helper (int32 vs int64 detected at runtime) ----------
__device__ __forceinline__ int edge_at(const void* p, int is64, int idx) {
  return is64 ? (int)((const long long*)p)[idx] : ((const int*)p)[idx];
}

__global__ void k_detect(const void* __restrict__ edges, int* __restrict__ flag) {
  if (threadIdx.x == 0 && blockIdx.x == 0) {
    const unsigned int* p = (const unsigned int*)edges;
    unsigned int odd = 0u, even = 0u;
    for (int i = 0; i < 256; ++i) { even |= p[2 * i]; odd |= p[2 * i + 1]; }
    flag[0] = (odd == 0u && even != 0u) ? 1 : 0;  // all-odd-zero => int64
  }
}

// ---------- counting sort pass 1: per-(bucket,block) histogram via LDS ----------
__global__ __launch_bounds__(256) void k_hist1(const void* __restrict__ edges,
                                               const int* __restrict__ flag,
                                               int* __restrict__ hist) {
  __shared__ int lh[1024];
  int tid = threadIdx.x, blk = blockIdx.x;
  for (int i = tid; i < NBK; i += 256) lh[i] = 0;
  __syncthreads();
  int f = flag[0];
  int e0 = blk * CHUNK, e1 = e0 + CHUNK;
  if (e1 > NE) e1 = NE;
  for (int e = e0 + tid; e < e1; e += 256) {
    int d = edge_at(edges, f, NE + e);
    atomicAdd(&lh[d >> 7], 1);
  }
  __syncthreads();
  for (int i = tid; i < NBK; i += 256) hist[i * NBLK + blk] = lh[i];
}

// ---------- generic exclusive scan (3 kernels), n up to 512*256 ----------
__global__ void k_scan_block(const int* __restrict__ in, int* __restrict__ outv,
                             int* __restrict__ bsums, int n) {
  __shared__ int s[256];
  int tid = threadIdx.x;
  int i = blockIdx.x * 256 + tid;
  int v = (i < n) ? in[i] : 0;
  s[tid] = v;
  __syncthreads();
  for (int off = 1; off < 256; off <<= 1) {
    int t = (tid >= off) ? s[tid - off] : 0;
    __syncthreads();
    s[tid] += t;
    __syncthreads();
  }
  if (i < n) outv[i] = s[tid] - v;
  if (tid == 255) bsums[blockIdx.x] = s[255];
}

__global__ void k_scan_sums(int* __restrict__ bsums, int nb) {
  __shared__ int s[512];
  int tid = threadIdx.x;
  int v = (tid < nb) ? bsums[tid] : 0;
  s[tid] = v;
  __syncthreads();
  for (int off = 1; off < 512; off <<= 1) {
    int t = (tid >= off) ? s[tid - off] : 0;
    __syncthreads();
    s[tid] += t;
    __syncthreads();
  }
  if (tid < nb) bsums[tid] = s[tid] - v;
}

__global__ void k_scan_add(int* __restrict__ outv, const int* __restrict__ bsums, int n) {
  int i = blockIdx.x * blockDim.x + threadIdx.x;
  if (i < n) outv[i] += bsums[i >> 8];
}

// ---------- counting sort pass 2: scatter records to exact slots ----------
// record = (dst&127)<<17 | src
__global__ __launch_bounds__(256) void k_scatter(const void* __restrict__ edges,
                                                 const int* __restrict__ flag,
                                                 const int* __restrict__ histS,
                                                 unsigned int* __restrict__ sorted) {
  __shared__ int base[1024];
  int tid = threadIdx.x, blk = blockIdx.x;
  for (int i = tid; i < NBK; i += 256) base[i] = histS[i * NBLK + blk];
  __syncthreads();
  int f = flag[0];
  int e0 = blk * CHUNK, e1 = e0 + CHUNK;
  if (e1 > NE) e1 = NE;
  for (int e = e0 + tid; e < e1; e += 256) {
    int s = edge_at(edges, f, e);
    int d = edge_at(edges, f, NE + e);
    int pos = atomicAdd(&base[d >> 7], 1);
    sorted[pos] = ((unsigned)(d & 127) << 17) | (unsigned)s;
  }
}

// ---------- pass B: bucket records -> node-ordered CSR + rowstart + dinv ----------
__global__ __launch_bounds__(256) void k_passB2(const unsigned int* __restrict__ sorted,
                                                const int* __restrict__ histS,
                                                int* __restrict__ rowstart,
                                                float* __restrict__ dinv,
                                                int* __restrict__ csr) {
  __shared__ int cnt[128];
  __shared__ int sc[256];
  __shared__ int fill[128];
  __shared__ int stage[4096];
  int b = blockIdx.x, tid = threadIdx.x;
  int ebase = histS[b * NBLK];
  int eend = (b + 1 < NBK) ? histS[(b + 1) * NBLK] : NE;
  int ne = eend - ebase;
  if (tid < 128) { cnt[tid] = 0; fill[tid] = 0; }
  __syncthreads();
  for (int i = tid; i < ne; i += 256) {
    unsigned int r = sorted[ebase + i];
    atomicAdd(&cnt[r >> 17], 1);
  }
  __syncthreads();
  int v = (tid < 128) ? cnt[tid] : 0;
  sc[tid] = v;
  __syncthreads();
  for (int off = 1; off < 256; off <<= 1) {
    int t = (tid >= off) ? sc[tid - off] : 0;
    __syncthreads();
    sc[tid] += t;
    __syncthreads();
  }
  // sc[tid] now inclusive; excl = sc[tid]-cnt[tid]
  int node = (b << 7) + tid;
  if (tid < 128 && node < NN) {
    rowstart[node] = ebase + sc[tid] - cnt[tid];
    dinv[node] = rsqrtf((float)(cnt[tid] + 1));  // +1 self loop
  }
  if (b == NBK - 1 && tid == 0) rowstart[NN] = NE;
  __syncthreads();
  for (int i = tid; i < ne; i += 256) {
    unsigned int r = sorted[ebase + i];
    int ld = (int)(r >> 17);
    int pos = atomicAdd(&fill[ld], 1);
    stage[sc[ld] - cnt[ld] + pos] = (int)(r & 0x1FFFFu);
  }
  __syncthreads();
  for (int i = tid; i < ne; i += 256) csr[ebase + i] = stage[i];
}

// ---------- fp32 -> bf16 convert with dinv pre-scale: xs[v] = dinv[v]*x[v] ----------
__global__ void k_cvt2(const float4* __restrict__ in, uint4* __restrict__ out,
                       const float* __restrict__ dinv) {
  int i = blockIdx.x * 256 + threadIdx.x;  // 8-element group; node = i>>4
  float dv = dinv[i >> 4];
  float4 a = in[(size_t)i * 2], b = in[(size_t)i * 2 + 1];
  uint4 o;
  o.x = packbf(a.x * dv, a.y * dv); o.y = packbf(a.z * dv, a.w * dv);
  o.z = packbf(b.x * dv, b.y * dv); o.w = packbf(b.z * dv, b.w * dv);
  out[i] = o;
}

// ---------- gather-aggregate core: acc = self + sum_src rows (pure adds) ----------
__device__ __forceinline__ void acc8(float* a, uint4 v) {
  a[0] += bflo(v.x); a[1] += bfhi(v.x); a[2] += bflo(v.y); a[3] += bfhi(v.y);
  a[4] += bflo(v.z); a[5] += bfhi(v.z); a[6] += bflo(v.w); a[7] += bfhi(v.w);
}

#define AGG_CORE(IN, NODE, L, A)                                                 \
  float A[8];                                                                    \
  {                                                                              \
    uint4 sv = IN[(size_t)(NODE)*16 + (L)];                                      \
    A[0] = bflo(sv.x); A[1] = bfhi(sv.x); A[2] = bflo(sv.y); A[3] = bfhi(sv.y);  \
    A[4] = bflo(sv.z); A[5] = bfhi(sv.z); A[6] = bflo(sv.w); A[7] = bfhi(sv.w);  \
  }                                                                              \
  {                                                                              \
    int i = rowstart[NODE], end = rowstart[(NODE) + 1];                          \
    for (; i + 7 < end; i += 8) {                                                \
      int s0 = csr[i], s1 = csr[i + 1], s2 = csr[i + 2], s3 = csr[i + 3];        \
      int s4 = csr[i + 4], s5 = csr[i + 5], s6 = csr[i + 6], s7 = csr[i + 7];    \
      uint4 v0 = IN[(size_t)s0 * 16 + (L)];                                      \
      uint4 v1 = IN[(size_t)s1 * 16 + (L)];                                      \
      uint4 v2 = IN[(size_t)s2 * 16 + (L)];                                      \
      uint4 v3 = IN[(size_t)s3 * 16 + (L)];                                      \
      uint4 v4 = IN[(size_t)s4 * 16 + (L)];                                      \
      uint4 v5 = IN[(size_t)s5 * 16 + (L)];                                      \
      uint4 v6 = IN[(size_t)s6 * 16 + (L)];                                      \
      uint4 v7 = IN[(size_t)s7 * 16 + (L)];                                      \
      acc8(A, v0); acc8(A, v1); acc8(A, v2); acc8(A, v3);                        \
      acc8(A, v4); acc8(A, v5); acc8(A, v6); acc8(A, v7);                        \
    }                                                                            \
    for (; i + 3 < end; i += 4) {                                                \
      int s0 = csr[i], s1 = csr[i + 1], s2 = csr[i + 2], s3 = csr[i + 3];        \
      uint4 v0 = IN[(size_t)s0 * 16 + (L)];                                      \
      uint4 v1 = IN[(size_t)s1 * 16 + (L)];                                      \
      uint4 v2 = IN[(size_t)s2 * 16 + (L)];                                      \
      uint4 v3 = IN[(size_t)s3 * 16 + (L)];                                      \
      acc8(A, v0); acc8(A, v1); acc8(A, v2); acc8(A, v3);                        \
    }                                                                            \
    for (; i < end; ++i) {                                                       \
      uint4 v0 = IN[(size_t)csr[i] * 16 + (L)];                                  \
      acc8(A, v0);                                                               \
    }                                                                            \
  }

// agg1: aggb[v] = bf16( dinv[v] * (xs[v] + sum xs[src]) )   [= Agg(x)[v]]
__global__ __launch_bounds__(256) void k_agg1(const uint4* __restrict__ in,
                                              uint4* __restrict__ out,
                                              const int* __restrict__ rowstart,
                                              const int* __restrict__ csr,
                                              const float* __restrict__ dinv) {
  int node = blockIdx.x * 16 + (threadIdx.x >> 4);
  int l = threadIdx.x & 15;
  AGG_CORE(in, node, l, a)
  float dv = dinv[node];
  uint4 o;
  o.x = packbf(a[0] * dv, a[1] * dv); o.y = packbf(a[2] * dv, a[3] * dv);
  o.z = packbf(a[4] * dv, a[5] * dv); o.w = packbf(a[6] * dv, a[7] * dv);
  out[(size_t)node * 16 + l] = o;
}

// agg2 + fused per-graph sum pool (16 nodes/block; block may span 2 graphs)
__global__ __launch_bounds__(256) void k_agg2p(const uint4* __restrict__ in,
                                               float* __restrict__ poolsum,
                                               const int* __restrict__ rowstart,
                                               const int* __restrict__ csr,
                                               const float* __restrict__ dinv) {
  __shared__ float sh[16][128];
  int nl = threadIdx.x >> 4, l = threadIdx.x & 15;
  int node = blockIdx.x * 16 + nl;
  AGG_CORE(in, node, l, a)
  float dv = dinv[node];
#pragma unroll
  for (int j = 0; j < 8; ++j) a[j] *= dv;
  *(float4*)&sh[nl][l * 8] = make_float4(a[0], a[1], a[2], a[3]);
  *(float4*)&sh[nl][l * 8 + 4] = make_float4(a[4], a[5], a[6], a[7]);
  __syncthreads();
  int tid = threadIdx.x;
  if (tid < 128) {
    int n0 = blockIdx.x * 16;
    int gA = n0 / 200;
    int split = (gA + 1) * 200 - n0;  // nodes [0,split) belong to gA
    if (split > 16) split = 16;
    float sA = 0.f, sB = 0.f;
#pragma unroll
    for (int n = 0; n < 16; ++n) {
      float v = sh[n][tid];
      if (n < split) sA += v; else sB += v;
    }
    atomicAdd(&poolsum[gA * 128 + tid], sA);
    if (split < 16) atomicAdd(&poolsum[(gA + 1) * 128 + tid], sB);
  }
}

// ---------- GEMM1 (MFMA bf16): h1s = bf16( dinv[r] * relu(A @ W1 + b1) ) ----------
__global__ __launch_bounds__(256) void k_gemm1m(const unsigned short* __restrict__ A,
                                                const float* __restrict__ W,
                                                const float* __restrict__ bias,
                                                const float* __restrict__ dinv,
                                                unsigned short* __restrict__ out, int M) {
  __shared__ unsigned short Wt[128 * 128];  // byte addr: c*256 + ((2k) ^ ((c&7)<<4))
  int tid = threadIdx.x;
  for (int i = tid; i < 8192; i += 256) {
    int c = i >> 6, kp = i & 63, k = kp * 2;
    float w0 = W[(size_t)k * 128 + c];
    float w1 = W[(size_t)(k + 1) * 128 + c];
    int off = (k * 2) ^ ((c & 7) << 4);
    *(unsigned int*)((char*)Wt + c * 256 + off) = packbf(w0, w1);
  }
  __syncthreads();

  int w = tid >> 6, lane = tid & 63;
  int m = lane & 15, g = lane >> 4;
  int row0 = blockIdx.x * 128 + w * 32;

  short8v afr[2][4];
#pragma unroll
  for (int rt = 0; rt < 2; ++rt) {
    int r = row0 + rt * 16 + m;
    bool ok = r < M;
    const unsigned short* ap = A + (size_t)r * 128 + g * 8;
#pragma unroll
    for (int ks = 0; ks < 4; ++ks) {
      short8v z;
#pragma unroll
      for (int j = 0; j < 8; ++j) z[j] = 0;
      afr[rt][ks] = ok ? *(const short8v*)(ap + ks * 32) : z;
    }
  }

  float4v acc[2][8];
#pragma unroll
  for (int rt = 0; rt < 2; ++rt)
#pragma unroll
    for (int ct = 0; ct < 8; ++ct) acc[rt][ct] = (float4v)0.f;

#pragma unroll
  for (int ks = 0; ks < 4; ++ks) {
    short8v bfr[8];
#pragma unroll
    for (int ct = 0; ct < 8; ++ct) {
      int c = ct * 16 + m;
      int off = (ks * 64 + g * 16) ^ ((c & 7) << 4);
      bfr[ct] = *(const short8v*)((const char*)Wt + c * 256 + off);
    }
#pragma unroll
    for (int rt = 0; rt < 2; ++rt)
#pragma unroll
      for (int ct = 0; ct < 8; ++ct)
        acc[rt][ct] = __builtin_amdgcn_mfma_f32_16x16x32_bf16(afr[rt][ks], bfr[ct],
                                                              acc[rt][ct], 0, 0, 0);
  }

#pragma unroll
  for (int rt = 0; rt < 2; ++rt) {
#pragma unroll
    for (int j = 0; j < 4; ++j) {
      int r = row0 + rt * 16 + g * 4 + j;
      if (r >= M) continue;
      float dv = dinv[r];
#pragma unroll
      for (int ct = 0; ct < 8; ++ct) {
        int c = ct * 16 + m;
        float v = fmaxf(acc[rt][ct][j] + bias[c], 0.f) * dv;
        out[(size_t)r * 128 + c] = (unsigned short)(packbf(v, 0.f) & 0xFFFFu);
      }
    }
  }
}

// ---------- GEMM2: fp32 A (scaled) @ fp32 W -> fp32 out ----------
__global__ __launch_bounds__(256) void k_gemm2(const float* __restrict__ A,
                                               const float* __restrict__ W,
                                               const float* __restrict__ bias,
                                               float* __restrict__ out, int M, float ascale) {
  __shared__ float Xs[32 * 132];
  __shared__ float Ws[32 * 128];
  const int tid = threadIdx.x;
  const int row0 = blockIdx.x * 128;
  const int rg = tid >> 4, cg = tid & 15;
  const int r0 = rg * 8, c0 = cg * 8;

  float bl[8];
#pragma unroll
  for (int j = 0; j < 8; ++j) bl[j] = bias[c0 + j];

  float acc[8][8];
#pragma unroll
  for (int i = 0; i < 8; ++i)
#pragma unroll
    for (int j = 0; j < 8; ++j) acc[i][j] = 0.f;

  for (int kt = 0; kt < 128; kt += 32) {
    __syncthreads();
#pragma unroll
    for (int i = tid; i < 1024; i += 256) {
      int r = i >> 3, c4 = i & 7;
      float4 v = make_float4(0.f, 0.f, 0.f, 0.f);
      if (row0 + r < M) v = *(const float4*)&A[(size_t)(row0 + r) * 128 + kt + c4 * 4];
      Xs[(c4 * 4 + 0) * 132 + r] = v.x * ascale;
      Xs[(c4 * 4 + 1) * 132 + r] = v.y * ascale;
      Xs[(c4 * 4 + 2) * 132 + r] = v.z * ascale;
      Xs[(c4 * 4 + 3) * 132 + r] = v.w * ascale;
    }
#pragma unroll
    for (int i = tid; i < 1024; i += 256) {
      int k = i >> 5, c4 = i & 31;
      *(float4*)&Ws[k * 128 + c4 * 4] = *(const float4*)&W[(size_t)(kt + k) * 128 + c4 * 4];
    }
    __syncthreads();
#pragma unroll 8
    for (int k = 0; k < 32; ++k) {
      float4 x0 = *(const float4*)&Xs[k * 132 + r0];
      float4 x1 = *(const float4*)&Xs[k * 132 + r0 + 4];
      float4 w0 = *(const float4*)&Ws[k * 128 + c0];
      float4 w1 = *(const float4*)&Ws[k * 128 + c0 + 4];
      float xr[8] = {x0.x, x0.y, x0.z, x0.w, x1.x, x1.y, x1.z, x1.w};
      float wr[8] = {w0.x, w0.y, w0.z, w0.w, w1.x, w1.y, w1.z, w1.w};
#pragma unroll
      for (int i = 0; i < 8; ++i)
#pragma unroll
        for (int j = 0; j < 8; ++j) acc[i][j] = fmaf(xr[i], wr[j], acc[i][j]);
    }
  }

#pragma unroll
  for (int i = 0; i < 8; ++i) {
    int r = row0 + r0 + i;
    if (r < M) {
      float o[8];
#pragma unroll
      for (int j = 0; j < 8; ++j) o[j] = acc[i][j] + bl[j];
      *(float4*)&out[(size_t)r * 128 + c0] = make_float4(o[0], o[1], o[2], o[3]);
      *(float4*)&out[(size_t)r * 128 + c0 + 4] = make_float4(o[4], o[5], o[6], o[7]);
    }
  }
}

extern "C" void kernel_launch(void* const* d_in, const int* in_sizes, int n_in,
                              void* d_out, int out_size, void* d_ws, size_t ws_size,
                              hipStream_t stream) {
  const float* x  = (const float*)d_in[0];
  const void* edges = d_in[1];
  const float* W1 = (const float*)d_in[3];
  const float* b1 = (const float*)d_in[4];
  const float* W2 = (const float*)d_in[5];
  const float* b2 = (const float*)d_in[6];
  float* out = (float*)d_out;

  // workspace layout (bytes), ~91.5 MB total
  char* ws = (char*)d_ws;
  float* poolsum  = (float*)(ws + 0);          // 256000  (zeroed)
  int*   flag     = (int*)(ws + 256000);       // 16
  int*   hist     = (int*)(ws + 256016);       // 400384  (NBK*NBLK, fully overwritten)
  int*   histS    = (int*)(ws + 656400);       // 400384  scanned
  int*   bsums    = (int*)(ws + 1056784);      // 2048
  int*   rowstart = (int*)(ws + 1058832);      // 400016
  float* dinv     = (float*)(ws + 1458848);    // 400000
  unsigned int* sorted = (unsigned int*)(ws + 1858848);  // 6.4 MB
  int*   csr      = (int*)(ws + 8258848);      // 6.4 MB
  void*  xs       = (void*)(ws + 14658848);    // 25.6 MB  bf16 dinv*x
  void*  aggb     = (void*)(ws + 40258848);    // 25.6 MB  bf16 Agg(x)
  void*  h1s      = (void*)(ws + 65858848);    // 25.6 MB  bf16 dinv*h1

  hipMemsetAsync(poolsum, 0, 256000, stream);

  const int NH = NBK * NBLK;  // 100096 histogram entries

  k_detect<<<1, 64, 0, stream>>>(edges, flag);
  k_hist1<<<NBLK, 256, 0, stream>>>(edges, flag, hist);
  k_scan_block<<<(NH + 255) / 256, 256, 0, stream>>>(hist, histS, bsums, NH);
  k_scan_sums<<<1, 512, 0, stream>>>(bsums, (NH + 255) / 256);
  k_scan_add<<<(NH + 255) / 256, 256, 0, stream>>>(histS, bsums, NH);
  k_scatter<<<NBLK, 256, 0, stream>>>(edges, flag, histS, sorted);
  k_passB2<<<NBK, 256, 0, stream>>>(sorted, histS, rowstart, dinv, csr);

  // xs = bf16(dinv * x)
  k_cvt2<<<NN * HD / 8 / 256, 256, 0, stream>>>((const float4*)x, (uint4*)xs, dinv);

  // conv1: aggb = dinv*(xs self+gather) = Agg(x); h1s = dinv*relu(aggb@W1+b1)
  k_agg1<<<NN / 16, 256, 0, stream>>>((const uint4*)xs, (uint4*)aggb, rowstart, csr, dinv);
  k_gemm1m<<<(NN + 127) / 128, 256, 0, stream>>>((const unsigned short*)aggb, W1, b1, dinv,
                                                 (unsigned short*)h1s, NN);
  // conv2 fused with pool: poolsum = sum_graph( dinv*(h1s self+gather) )
  k_agg2p<<<NN / 16, 256, 0, stream>>>((const uint4*)h1s, poolsum, rowstart, csr, dinv);
  k_gemm2<<<(NG + 127) / 128, 256, 0, stream>>>(poolsum, W2, b2, out, NG, 1.f / (float)NPG);
}

// Round 5
// 289.649 us; speedup vs baseline: 2.4385x; 1.0971x over previous
//
#include <hip/hip_runtime.h>
#include <hip/hip_bf16.h>
#include <stdint.h>

#define NN 100000
#define NE 1600000
#define HD 128
#define NG 500
#define NPG 200

#define NBK 782      // node buckets of 128: ceil(NN/128)
#define NBLK 128     // scatter blocks
#define CHUNK 12500  // edges per scatter block (NBLK*CHUNK == NE)

typedef __attribute__((ext_vector_type(8))) short short8v;
typedef __attribute__((ext_vector_type(4))) float float4v;

// ---------- bf16 helpers (bit-level, RNE) ----------
__device__ __forceinline__ float bflo(unsigned int u) { return __uint_as_float(u << 16); }
__device__ __forceinline__ float bfhi(unsigned int u) { return __uint_as_float(u & 0xffff0000u); }
__device__ __forceinline__ unsigned int packbf(float a, float b) {
  unsigned int ua = __float_as_uint(a), ub = __float_as_uint(b);
  ua += 0x7fffu + ((ua >> 16) & 1u);
  ub += 0x7fffu + ((ub >> 16) & 1u);
  return (ua >> 16) | (ub & 0xffff0000u);
}

// ---------- edge dtype helper (int32 vs int64 detected at runtime) ----------
__device__ __forceinline__ int edge_at(const void* p, int is64, int idx) {
  return is64 ? (int)((const long long*)p)[idx] : ((const int*)p)[idx];
}

__global__ void k_detect(const void* __restrict__ edges, int* __restrict__ flag) {
  if (threadIdx.x == 0 && blockIdx.x == 0) {
    const unsigned int* p = (const unsigned int*)edges;
    unsigned int odd = 0u, even = 0u;
    for (int i = 0; i < 256; ++i) { even |= p[2 * i]; odd |= p[2 * i + 1]; }
    flag[0] = (odd == 0u && even != 0u) ? 1 : 0;  // all-odd-zero => int64
  }
}

// ---------- counting sort pass 1: per-(bucket,block) histogram via LDS ----------
__global__ __launch_bounds__(256) void k_hist1(const void* __restrict__ edges,
                                               const int* __restrict__ flag,
                                               int* __restrict__ hist) {
  __shared__ int lh[1024];
  int tid = threadIdx.x, blk = blockIdx.x;
  for (int i = tid; i < NBK; i += 256) lh[i] = 0;
  __syncthreads();
  int f = flag[0];
  int e0 = blk * CHUNK, e1 = e0 + CHUNK;
  if (e1 > NE) e1 = NE;
  for (int e = e0 + tid; e < e1; e += 256) {
    int d = edge_at(edges, f, NE + e);
    atomicAdd(&lh[d >> 7], 1);
  }
  __syncthreads();
  for (int i = tid; i < NBK; i += 256) hist[i * NBLK + blk] = lh[i];
}

// ---------- generic exclusive scan (3 kernels) ----------
__global__ void k_scan_block(const int* __restrict__ in, int* __restrict__ outv,
                             int* __restrict__ bsums, int n) {
  __shared__ int s[256];
  int tid = threadIdx.x;
  int i = blockIdx.x * 256 + tid;
  int v = (i < n) ? in[i] : 0;
  s[tid] = v;
  __syncthreads();
  for (int off = 1; off < 256; off <<= 1) {
    int t = (tid >= off) ? s[tid - off] : 0;
    __syncthreads();
    s[tid] += t;
    __syncthreads();
  }
  if (i < n) outv[i] = s[tid] - v;
  if (tid == 255) bsums[blockIdx.x] = s[255];
}

__global__ void k_scan_sums(int* __restrict__ bsums, int nb) {
  __shared__ int s[512];
  int tid = threadIdx.x;
  int v = (tid < nb) ? bsums[tid] : 0;
  s[tid] = v;
  __syncthreads();
  for (int off = 1; off < 512; off <<= 1) {
    int t = (tid >= off) ? s[tid - off] : 0;
    __syncthreads();
    s[tid] += t;
    __syncthreads();
  }
  if (tid < nb) bsums[tid] = s[tid] - v;
}

__global__ void k_scan_add(int* __restrict__ outv, const int* __restrict__ bsums, int n) {
  int i = blockIdx.x * blockDim.x + threadIdx.x;
  if (i < n) outv[i] += bsums[i >> 8];
}

// ---------- counting sort pass 2: scatter records to exact slots ----------
// record = (dst&127)<<17 | src
__global__ __launch_bounds__(256) void k_scatter(const void* __restrict__ edges,
                                                 const int* __restrict__ flag,
                                                 const int* __restrict__ histS,
                                                 unsigned int* __restrict__ sorted) {
  __shared__ int base[1024];
  int tid = threadIdx.x, blk = blockIdx.x;
  for (int i = tid; i < NBK; i += 256) base[i] = histS[i * NBLK + blk];
  __syncthreads();
  int f = flag[0];
  int e0 = blk * CHUNK, e1 = e0 + CHUNK;
  if (e1 > NE) e1 = NE;
  for (int e = e0 + tid; e < e1; e += 256) {
    int s = edge_at(edges, f, e);
    int d = edge_at(edges, f, NE + e);
    int pos = atomicAdd(&base[d >> 7], 1);
    sorted[pos] = ((unsigned)(d & 127) << 17) | (unsigned)s;
  }
}

// ---------- pass B: bucket records -> node-ordered CSR + rowstart + dinv ----------
__global__ __launch_bounds__(256) void k_passB2(const unsigned int* __restrict__ sorted,
                                                const int* __restrict__ histS,
                                                int* __restrict__ rowstart,
                                                float* __restrict__ dinv,
                                                int* __restrict__ csr) {
  __shared__ int cnt[128];
  __shared__ int sc[256];
  __shared__ int fill[128];
  __shared__ int stage[4096];
  int b = blockIdx.x, tid = threadIdx.x;
  int ebase = histS[b * NBLK];
  int eend = (b + 1 < NBK) ? histS[(b + 1) * NBLK] : NE;
  int ne = eend - ebase;
  if (tid < 128) { cnt[tid] = 0; fill[tid] = 0; }
  __syncthreads();
  for (int i = tid; i < ne; i += 256) {
    unsigned int r = sorted[ebase + i];
    atomicAdd(&cnt[r >> 17], 1);
  }
  __syncthreads();
  int v = (tid < 128) ? cnt[tid] : 0;
  sc[tid] = v;
  __syncthreads();
  for (int off = 1; off < 256; off <<= 1) {
    int t = (tid >= off) ? sc[tid - off] : 0;
    __syncthreads();
    sc[tid] += t;
    __syncthreads();
  }
  int node = (b << 7) + tid;
  if (tid < 128 && node < NN) {
    rowstart[node] = ebase + sc[tid] - cnt[tid];
    dinv[node] = rsqrtf((float)(cnt[tid] + 1));  // +1 self loop
  }
  if (b == NBK - 1 && tid == 0) rowstart[NN] = NE;
  __syncthreads();
  for (int i = tid; i < ne; i += 256) {
    unsigned int r = sorted[ebase + i];
    int ld = (int)(r >> 17);
    int pos = atomicAdd(&fill[ld], 1);
    stage[sc[ld] - cnt[ld] + pos] = (int)(r & 0x1FFFFu);
  }
  __syncthreads();
  for (int i = tid; i < ne; i += 256) csr[ebase + i] = stage[i];
}

// ---------- degree-balanced order: counting sort by degree within each graph ----------
__global__ __launch_bounds__(256) void k_order(const int* __restrict__ rowstart,
                                               int* __restrict__ order) {
  __shared__ int h[128];
  __shared__ int sc[256];
  __shared__ int fill[128];
  __shared__ int degs[256];
  int g = blockIdx.x, tid = threadIdx.x;
  if (tid < 128) { h[tid] = 0; fill[tid] = 0; }
  __syncthreads();
  if (tid < NPG) {
    int n = g * NPG + tid;
    int d = rowstart[n + 1] - rowstart[n];
    if (d > 127) d = 127;
    degs[tid] = d;
    atomicAdd(&h[d], 1);
  }
  __syncthreads();
  int v = (tid < 128) ? h[tid] : 0;
  sc[tid] = v;
  __syncthreads();
  for (int off = 1; off < 256; off <<= 1) {
    int t = (tid >= off) ? sc[tid - off] : 0;
    __syncthreads();
    sc[tid] += t;
    __syncthreads();
  }
  if (tid < NPG) {
    int d = degs[tid];
    int pos = sc[d] - h[d] + atomicAdd(&fill[d], 1);
    order[g * NPG + pos] = g * NPG + tid;
  }
}

// ---------- fp32 -> bf16 convert with dinv pre-scale: xs[v] = dinv[v]*x[v] ----------
__global__ void k_cvt2(const float4* __restrict__ in, uint4* __restrict__ out,
                       const float* __restrict__ dinv) {
  int i = blockIdx.x * 256 + threadIdx.x;  // 8-element group; node = i>>4
  float dv = dinv[i >> 4];
  float4 a = in[(size_t)i * 2], b = in[(size_t)i * 2 + 1];
  uint4 o;
  o.x = packbf(a.x * dv, a.y * dv); o.y = packbf(a.z * dv, a.w * dv);
  o.z = packbf(b.x * dv, b.y * dv); o.w = packbf(b.z * dv, b.w * dv);
  out[i] = o;
}

// ---------- W1 fp32 [128][128] -> bf16 transposed W1t[c][k] ----------
__global__ void k_cvtW(const float* __restrict__ W, unsigned int* __restrict__ Wt) {
  int i = blockIdx.x * 256 + threadIdx.x;  // 0..8191
  int c = i >> 6, kp = i & 63;
  float w0 = W[(size_t)(2 * kp) * 128 + c];
  float w1 = W[(size_t)(2 * kp + 1) * 128 + c];
  Wt[c * 64 + kp] = packbf(w0, w1);
}

// ---------- gather-aggregate core: acc = self + sum_src rows (pure adds) ----------
__device__ __forceinline__ void acc8(float* a, uint4 v) {
  a[0] += bflo(v.x); a[1] += bfhi(v.x); a[2] += bflo(v.y); a[3] += bfhi(v.y);
  a[4] += bflo(v.z); a[5] += bfhi(v.z); a[6] += bflo(v.w); a[7] += bfhi(v.w);
}

#define AGG_CORE(IN, NODE, L, A)                                                 \
  float A[8];                                                                    \
  {                                                                              \
    uint4 sv = IN[(size_t)(NODE)*16 + (L)];                                      \
    A[0] = bflo(sv.x); A[1] = bfhi(sv.x); A[2] = bflo(sv.y); A[3] = bfhi(sv.y);  \
    A[4] = bflo(sv.z); A[5] = bfhi(sv.z); A[6] = bflo(sv.w); A[7] = bfhi(sv.w);  \
  }                                                                              \
  {                                                                              \
    int i = rowstart[NODE], end = rowstart[(NODE) + 1];                          \
    for (; i + 7 < end; i += 8) {                                                \
      int s0 = csr[i], s1 = csr[i + 1], s2 = csr[i + 2], s3 = csr[i + 3];        \
      int s4 = csr[i + 4], s5 = csr[i + 5], s6 = csr[i + 6], s7 = csr[i + 7];    \
      uint4 v0 = IN[(size_t)s0 * 16 + (L)];                                      \
      uint4 v1 = IN[(size_t)s1 * 16 + (L)];                                      \
      uint4 v2 = IN[(size_t)s2 * 16 + (L)];                                      \
      uint4 v3 = IN[(size_t)s3 * 16 + (L)];                                      \
      uint4 v4 = IN[(size_t)s4 * 16 + (L)];                                      \
      uint4 v5 = IN[(size_t)s5 * 16 + (L)];                                      \
      uint4 v6 = IN[(size_t)s6 * 16 + (L)];                                      \
      uint4 v7 = IN[(size_t)s7 * 16 + (L)];                                      \
      acc8(A, v0); acc8(A, v1); acc8(A, v2); acc8(A, v3);                        \
      acc8(A, v4); acc8(A, v5); acc8(A, v6); acc8(A, v7);                        \
    }                                                                            \
    for (; i + 3 < end; i += 4) {                                                \
      int s0 = csr[i], s1 = csr[i + 1], s2 = csr[i + 2], s3 = csr[i + 3];        \
      uint4 v0 = IN[(size_t)s0 * 16 + (L)];                                      \
      uint4 v1 = IN[(size_t)s1 * 16 + (L)];                                      \
      uint4 v2 = IN[(size_t)s2 * 16 + (L)];                                      \
      uint4 v3 = IN[(size_t)s3 * 16 + (L)];                                      \
      acc8(A, v0); acc8(A, v1); acc8(A, v2); acc8(A, v3);                        \
    }                                                                            \
    for (; i < end; ++i) {                                                       \
      uint4 v0 = IN[(size_t)csr[i] * 16 + (L)];                                  \
      acc8(A, v0);                                                               \
    }                                                                            \
  }

// ---------- fused agg1 + GEMM1 (MFMA): h1s[v] = bf16(dinv*relu(Agg(x)@W1+b1)) ----------
// Block = 16 nodes (degree-sorted) = one 16x128 A-tile. 4 waves x 2 col-tiles MFMA.
__global__ __launch_bounds__(256) void k_agg1g(const uint4* __restrict__ in,
                                               const unsigned int* __restrict__ W1t,
                                               const float* __restrict__ bias,
                                               uint4* __restrict__ out,
                                               const int* __restrict__ rowstart,
                                               const int* __restrict__ csr,
                                               const float* __restrict__ dinv,
                                               const int* __restrict__ order) {
  __shared__ uint4 At[16 * 16];   // bf16 A-tile, row r chunk s at At[r*16 + (s^(r&7))]
  __shared__ float Ot[16 * 128];  // f32 out-tile, elem (r,c) at byte r*512 + ((c*4)^((r&7)<<4))
  __shared__ float sdv[16];
  int tid = threadIdx.x;
  int qw = tid >> 4, l = tid & 15;
  int pos = blockIdx.x * 16 + qw;
  int node = order[pos];
  AGG_CORE(in, node, l, a)
  float dv = dinv[node];
  if (l == 0) sdv[qw] = dv;
  {
    uint4 o;
    o.x = packbf(a[0] * dv, a[1] * dv); o.y = packbf(a[2] * dv, a[3] * dv);
    o.z = packbf(a[4] * dv, a[5] * dv); o.w = packbf(a[6] * dv, a[7] * dv);
    At[qw * 16 + (l ^ (qw & 7))] = o;
  }
  __syncthreads();

  // MFMA: wave w covers col-tiles {2w, 2w+1}
  int w = tid >> 6, lane = tid & 63;
  int m = lane & 15, g = lane >> 4;
  float4v acc[2];
  acc[0] = (float4v)0.f;
  acc[1] = (float4v)0.f;
#pragma unroll
  for (int ks = 0; ks < 4; ++ks) {
    int slot = ks * 4 + g;
    short8v af = *(const short8v*)&At[m * 16 + (slot ^ (m & 7))];
#pragma unroll
    for (int t = 0; t < 2; ++t) {
      int c = (w * 2 + t) * 16 + m;
      short8v bf = *(const short8v*)&W1t[c * 64 + ks * 16 + g * 4];
      acc[t] = __builtin_amdgcn_mfma_f32_16x16x32_bf16(af, bf, acc[t], 0, 0, 0);
    }
  }
  // epilogue: bias + relu + dinv prescale -> swizzled f32 tile
#pragma unroll
  for (int t = 0; t < 2; ++t) {
    int c = (w * 2 + t) * 16 + m;
    float bl = bias[c];
#pragma unroll
    for (int j = 0; j < 4; ++j) {
      int r = g * 4 + j;
      float v = fmaxf(acc[t][j] + bl, 0.f) * sdv[r];
      *(float*)((char*)Ot + r * 512 + ((c * 4) ^ ((r & 7) << 4))) = v;
    }
  }
  __syncthreads();
  // readout: quarter-wave qw streams row qw (256 B coalesced)
  {
    int s = (qw & 7) << 4;
    const char* base = (const char*)Ot + qw * 512;
    float4 f0 = *(const float4*)(base + ((l * 32) ^ s));
    float4 f1 = *(const float4*)(base + ((l * 32 + 16) ^ s));
    uint4 r;
    r.x = packbf(f0.x, f0.y); r.y = packbf(f0.z, f0.w);
    r.z = packbf(f1.x, f1.y); r.w = packbf(f1.z, f1.w);
    out[(size_t)node * 16 + l] = r;
  }
}

// agg2 + fused per-graph sum pool (16 degree-sorted nodes/block; pos->graph as before)
__global__ __launch_bounds__(256) void k_agg2p(const uint4* __restrict__ in,
                                               float* __restrict__ poolsum,
                                               const int* __restrict__ rowstart,
                                               const int* __restrict__ csr,
                                               const float* __restrict__ dinv,
                                               const int* __restrict__ order) {
  __shared__ float sh[16][128];
  int nl = threadIdx.x >> 4, l = threadIdx.x & 15;
  int pos = blockIdx.x * 16 + nl;
  int node = order[pos];
  AGG_CORE(in, node, l, a)
  float dv = dinv[node];
#pragma unroll
  for (int j = 0; j < 8; ++j) a[j] *= dv;
  *(float4*)&sh[nl][l * 8] = make_float4(a[0], a[1], a[2], a[3]);
  *(float4*)&sh[nl][l * 8 + 4] = make_float4(a[4], a[5], a[6], a[7]);
  __syncthreads();
  int tid = threadIdx.x;
  if (tid < 128) {
    int n0 = blockIdx.x * 16;
    int gA = n0 / NPG;
    int split = (gA + 1) * NPG - n0;  // positions [0,split) belong to gA
    if (split > 16) split = 16;
    float sA = 0.f, sB = 0.f;
#pragma unroll
    for (int n = 0; n < 16; ++n) {
      float v = sh[n][tid];
      if (n < split) sA += v; else sB += v;
    }
    atomicAdd(&poolsum[gA * 128 + tid], sA);
    if (split < 16) atomicAdd(&poolsum[(gA + 1) * 128 + tid], sB);
  }
}

// ---------- GEMM2: fp32 A (scaled) @ fp32 W -> fp32 out ----------
__global__ __launch_bounds__(256) void k_gemm2(const float* __restrict__ A,
                                               const float* __restrict__ W,
                                               const float* __restrict__ bias,
                                               float* __restrict__ out, int M, float ascale) {
  __shared__ float Xs[32 * 132];
  __shared__ float Ws[32 * 128];
  const int tid = threadIdx.x;
  const int row0 = blockIdx.x * 128;
  const int rg = tid >> 4, cg = tid & 15;
  const int r0 = rg * 8, c0 = cg * 8;

  float bl[8];
#pragma unroll
  for (int j = 0; j < 8; ++j) bl[j] = bias[c0 + j];

  float acc[8][8];
#pragma unroll
  for (int i = 0; i < 8; ++i)
#pragma unroll
    for (int j = 0; j < 8; ++j) acc[i][j] = 0.f;

  for (int kt = 0; kt < 128; kt += 32) {
    __syncthreads();
#pragma unroll
    for (int i = tid; i < 1024; i += 256) {
      int r = i >> 3, c4 = i & 7;
      float4 v = make_float4(0.f, 0.f, 0.f, 0.f);
      if (row0 + r < M) v = *(const float4*)&A[(size_t)(row0 + r) * 128 + kt + c4 * 4];
      Xs[(c4 * 4 + 0) * 132 + r] = v.x * ascale;
      Xs[(c4 * 4 + 1) * 132 + r] = v.y * ascale;
      Xs[(c4 * 4 + 2) * 132 + r] = v.z * ascale;
      Xs[(c4 * 4 + 3) * 132 + r] = v.w * ascale;
    }
#pragma unroll
    for (int i = tid; i < 1024; i += 256) {
      int k = i >> 5, c4 = i & 31;
      *(float4*)&Ws[k * 128 + c4 * 4] = *(const float4*)&W[(size_t)(kt + k) * 128 + c4 * 4];
    }
    __syncthreads();
#pragma unroll 8
    for (int k = 0; k < 32; ++k) {
      float4 x0 = *(const float4*)&Xs[k * 132 + r0];
      float4 x1 = *(const float4*)&Xs[k * 132 + r0 + 4];
      float4 w0 = *(const float4*)&Ws[k * 128 + c0];
      float4 w1 = *(const float4*)&Ws[k * 128 + c0 + 4];
      float xr[8] = {x0.x, x0.y, x0.z, x0.w, x1.x, x1.y, x1.z, x1.w};
      float wr[8] = {w0.x, w0.y, w0.z, w0.w, w1.x, w1.y, w1.z, w1.w};
#pragma unroll
      for (int i = 0; i < 8; ++i)
#pragma unroll
        for (int j = 0; j < 8; ++j) acc[i][j] = fmaf(xr[i], wr[j], acc[i][j]);
    }
  }

#pragma unroll
  for (int i = 0; i < 8; ++i) {
    int r = row0 + r0 + i;
    if (r < M) {
      float o[8];
#pragma unroll
      for (int j = 0; j < 8; ++j) o[j] = acc[i][j] + bl[j];
      *(float4*)&out[(size_t)r * 128 + c0] = make_float4(o[0], o[1], o[2], o[3]);
      *(float4*)&out[(size_t)r * 128 + c0 + 4] = make_float4(o[4], o[5], o[6], o[7]);
    }
  }
}

extern "C" void kernel_launch(void* const* d_in, const int* in_sizes, int n_in,
                              void* d_out, int out_size, void* d_ws, size_t ws_size,
                              hipStream_t stream) {
  const float* x  = (const float*)d_in[0];
  const void* edges = d_in[1];
  const float* W1 = (const float*)d_in[3];
  const float* b1 = (const float*)d_in[4];
  const float* W2 = (const float*)d_in[5];
  const float* b2 = (const float*)d_in[6];
  float* out = (float*)d_out;

  // workspace layout (bytes), ~66.3 MB total
  char* ws = (char*)d_ws;
  float* poolsum  = (float*)(ws + 0);          // 256000  (zeroed)
  int*   flag     = (int*)(ws + 256000);       // 16
  int*   hist     = (int*)(ws + 256016);       // 400384
  int*   histS    = (int*)(ws + 656400);       // 400384
  int*   bsums    = (int*)(ws + 1056784);      // 2048
  int*   rowstart = (int*)(ws + 1058832);      // 400016
  float* dinv     = (float*)(ws + 1458848);    // 400000
  int*   order    = (int*)(ws + 1858848);      // 400000
  unsigned int* W1t = (unsigned int*)(ws + 2258848);     // 32768 (bf16 W1^T)
  unsigned int* sorted = (unsigned int*)(ws + 2291616);  // 6.4 MB
  int*   csr      = (int*)(ws + 8691616);      // 6.4 MB
  void*  xs       = (void*)(ws + 15091616);    // 25.6 MB  bf16 dinv*x
  void*  h1s      = (void*)(ws + 40691616);    // 25.6 MB  bf16 dinv*h1

  hipMemsetAsync(poolsum, 0, 256000, stream);

  const int NH = NBK * NBLK;  // 100096 histogram entries

  k_detect<<<1, 64, 0, stream>>>(edges, flag);
  k_hist1<<<NBLK, 256, 0, stream>>>(edges, flag, hist);
  k_scan_block<<<(NH + 255) / 256, 256, 0, stream>>>(hist, histS, bsums, NH);
  k_scan_sums<<<1, 512, 0, stream>>>(bsums, (NH + 255) / 256);
  k_scan_add<<<(NH + 255) / 256, 256, 0, stream>>>(histS, bsums, NH);
  k_scatter<<<NBLK, 256, 0, stream>>>(edges, flag, histS, sorted);
  k_passB2<<<NBK, 256, 0, stream>>>(sorted, histS, rowstart, dinv, csr);
  k_order<<<NG, 256, 0, stream>>>(rowstart, order);

  // xs = bf16(dinv * x); W1t = bf16(W1^T)
  k_cvt2<<<NN * HD / 8 / 256, 256, 0, stream>>>((const float4*)x, (uint4*)xs, dinv);
  k_cvtW<<<32, 256, 0, stream>>>(W1, W1t);

  // conv1 fused: h1s = bf16( dinv * relu( Agg(x) @ W1 + b1 ) )
  k_agg1g<<<NN / 16, 256, 0, stream>>>((const uint4*)xs, W1t, b1, (uint4*)h1s,
                                       rowstart, csr, dinv, order);
  // conv2 fused with pool: poolsum = sum_graph( dinv*(h1s self+gather) )
  k_agg2p<<<NN / 16, 256, 0, stream>>>((const uint4*)h1s, poolsum, rowstart, csr, dinv, order);
  k_gemm2<<<(NG + 127) / 128, 256, 0, stream>>>(poolsum, W2, b2, out, NG, 1.f / (float)NPG);
}

// Round 6
// 206.084 us; speedup vs baseline: 3.4272x; 1.4055x over previous
//
#include <hip/hip_runtime.h>
#include <hip/hip_bf16.h>
#include <stdint.h>

#define NN 100000
#define NE 1600000
#define HD 128
#define NG 500
#define NPG 200

#define NBK 782      // node buckets of 128: ceil(NN/128)
#define NBLK 128     // scatter blocks
#define CHUNK 12500  // edges per scatter block (NBLK*CHUNK == NE)

typedef __attribute__((ext_vector_type(8))) short short8v;
typedef __attribute__((ext_vector_type(4))) float float4v;
typedef __attribute__((ext_vector_type(2))) float float2v;

// ---------- bf16 helpers (bit-level, RNE) ----------
__device__ __forceinline__ float bflo(unsigned int u) { return __uint_as_float(u << 16); }
__device__ __forceinline__ float bfhi(unsigned int u) { return __uint_as_float(u & 0xffff0000u); }
__device__ __forceinline__ unsigned int packbf(float a, float b) {
  unsigned int ua = __float_as_uint(a), ub = __float_as_uint(b);
  ua += 0x7fffu + ((ua >> 16) & 1u);
  ub += 0x7fffu + ((ub >> 16) & 1u);
  return (ua >> 16) | (ub & 0xffff0000u);
}

// ---------- edge dtype helper (int32 vs int64 detected in-kernel) ----------
__device__ __forceinline__ int edge_at(const void* p, int is64, int idx) {
  return is64 ? (int)((const long long*)p)[idx] : ((const int*)p)[idx];
}

// all 256 threads participate; sf is one LDS int
__device__ __forceinline__ int detect_is64(const void* edges, int tid, int* sf) {
  if (tid == 0) *sf = 0;
  __syncthreads();
  const unsigned int* p = (const unsigned int*)edges;
  unsigned int e = p[2 * tid], o = p[2 * tid + 1];
  unsigned int m = (e ? 1u : 0u) | (o ? 2u : 0u);
  if (m) atomicOr(sf, (int)m);
  __syncthreads();
  int v = *sf;
  return ((v & 2) == 0) && (v & 1);  // all-odd-zero & some-even-nonzero => int64
}

// ---------- counting sort pass 1: per-(bucket,block) histogram via LDS ----------
__global__ __launch_bounds__(256) void k_hist1(const void* __restrict__ edges,
                                               int* __restrict__ hist) {
  __shared__ int lh[1024];
  __shared__ int sf;
  int tid = threadIdx.x, blk = blockIdx.x;
  int f = detect_is64(edges, tid, &sf);
  for (int i = tid; i < NBK; i += 256) lh[i] = 0;
  __syncthreads();
  int e0 = blk * CHUNK, e1 = e0 + CHUNK;
  if (e1 > NE) e1 = NE;
  for (int e = e0 + tid; e < e1; e += 256) {
    int d = edge_at(edges, f, NE + e);
    atomicAdd(&lh[d >> 7], 1);
  }
  __syncthreads();
  for (int i = tid; i < NBK; i += 256) hist[i * NBLK + blk] = lh[i];
}

// ---------- generic exclusive scan (3 kernels) ----------
__global__ void k_scan_block(const int* __restrict__ in, int* __restrict__ outv,
                             int* __restrict__ bsums, int n) {
  __shared__ int s[256];
  int tid = threadIdx.x;
  int i = blockIdx.x * 256 + tid;
  int v = (i < n) ? in[i] : 0;
  s[tid] = v;
  __syncthreads();
  for (int off = 1; off < 256; off <<= 1) {
    int t = (tid >= off) ? s[tid - off] : 0;
    __syncthreads();
    s[tid] += t;
    __syncthreads();
  }
  if (i < n) outv[i] = s[tid] - v;
  if (tid == 255) bsums[blockIdx.x] = s[255];
}

__global__ void k_scan_sums(int* __restrict__ bsums, int nb) {
  __shared__ int s[512];
  int tid = threadIdx.x;
  int v = (tid < nb) ? bsums[tid] : 0;
  s[tid] = v;
  __syncthreads();
  for (int off = 1; off < 512; off <<= 1) {
    int t = (tid >= off) ? s[tid - off] : 0;
    __syncthreads();
    s[tid] += t;
    __syncthreads();
  }
  if (tid < nb) bsums[tid] = s[tid] - v;
}

__global__ void k_scan_add(int* __restrict__ outv, const int* __restrict__ bsums, int n) {
  int i = blockIdx.x * blockDim.x + threadIdx.x;
  if (i < n) outv[i] += bsums[i >> 8];
}

// ---------- counting sort pass 2: scatter records to exact slots ----------
// record = (dst&127)<<17 | src
__global__ __launch_bounds__(256) void k_scatter(const void* __restrict__ edges,
                                                 const int* __restrict__ histS,
                                                 unsigned int* __restrict__ sorted) {
  __shared__ int base[1024];
  __shared__ int sf;
  int tid = threadIdx.x, blk = blockIdx.x;
  int f = detect_is64(edges, tid, &sf);
  for (int i = tid; i < NBK; i += 256) base[i] = histS[i * NBLK + blk];
  __syncthreads();
  int e0 = blk * CHUNK, e1 = e0 + CHUNK;
  if (e1 > NE) e1 = NE;
  for (int e = e0 + tid; e < e1; e += 256) {
    int s = edge_at(edges, f, e);
    int d = edge_at(edges, f, NE + e);
    int pos = atomicAdd(&base[d >> 7], 1);
    sorted[pos] = ((unsigned)(d & 127) << 17) | (unsigned)s;
  }
}

// ---------- pass B: bucket records -> node-ordered CSR + rowstart + dinv ----------
__global__ __launch_bounds__(256) void k_passB2(const unsigned int* __restrict__ sorted,
                                                const int* __restrict__ histS,
                                                int* __restrict__ rowstart,
                                                float* __restrict__ dinv,
                                                int* __restrict__ csr) {
  __shared__ int cnt[128];
  __shared__ int sc[256];
  __shared__ int fill[128];
  __shared__ int stage[4096];
  int b = blockIdx.x, tid = threadIdx.x;
  int ebase = histS[b * NBLK];
  int eend = (b + 1 < NBK) ? histS[(b + 1) * NBLK] : NE;
  int ne = eend - ebase;
  if (tid < 128) { cnt[tid] = 0; fill[tid] = 0; }
  __syncthreads();
  for (int i = tid; i < ne; i += 256) {
    unsigned int r = sorted[ebase + i];
    atomicAdd(&cnt[r >> 17], 1);
  }
  __syncthreads();
  int v = (tid < 128) ? cnt[tid] : 0;
  sc[tid] = v;
  __syncthreads();
  for (int off = 1; off < 256; off <<= 1) {
    int t = (tid >= off) ? sc[tid - off] : 0;
    __syncthreads();
    sc[tid] += t;
    __syncthreads();
  }
  int node = (b << 7) + tid;
  if (tid < 128 && node < NN) {
    rowstart[node] = ebase + sc[tid] - cnt[tid];
    dinv[node] = rsqrtf((float)(cnt[tid] + 1));  // +1 self loop
  }
  if (b == NBK - 1 && tid == 0) rowstart[NN] = NE;
  __syncthreads();
  for (int i = tid; i < ne; i += 256) {
    unsigned int r = sorted[ebase + i];
    int ld = (int)(r >> 17);
    int pos = atomicAdd(&fill[ld], 1);
    stage[sc[ld] - cnt[ld] + pos] = (int)(r & 0x1FFFFu);
  }
  __syncthreads();
  for (int i = tid; i < ne; i += 256) csr[ebase + i] = stage[i];
}

// ---------- degree-balanced order: counting sort by degree within each graph ----------
__global__ __launch_bounds__(256) void k_order(const int* __restrict__ rowstart,
                                               int* __restrict__ order) {
  __shared__ int h[128];
  __shared__ int sc[256];
  __shared__ int fill[128];
  __shared__ int degs[256];
  int g = blockIdx.x, tid = threadIdx.x;
  if (tid < 128) { h[tid] = 0; fill[tid] = 0; }
  __syncthreads();
  if (tid < NPG) {
    int n = g * NPG + tid;
    int d = rowstart[n + 1] - rowstart[n];
    if (d > 127) d = 127;
    degs[tid] = d;
    atomicAdd(&h[d], 1);
  }
  __syncthreads();
  int v = (tid < 128) ? h[tid] : 0;
  sc[tid] = v;
  __syncthreads();
  for (int off = 1; off < 256; off <<= 1) {
    int t = (tid >= off) ? sc[tid - off] : 0;
    __syncthreads();
    sc[tid] += t;
    __syncthreads();
  }
  if (tid < NPG) {
    int d = degs[tid];
    int pos = sc[d] - h[d] + atomicAdd(&fill[d], 1);
    order[g * NPG + pos] = g * NPG + tid;
  }
}

// ---------- fp32 -> fp8 convert with prescale: xs8[v] = fp8(8 * dinv[v] * x[v]) ----------
__global__ void k_cvt8(const float4* __restrict__ in, uint2* __restrict__ out,
                       const float* __restrict__ dinv) {
  int i = blockIdx.x * 256 + threadIdx.x;  // 8-element group; node = i>>4
  float s = dinv[i >> 4] * 8.f;
  float4 a = in[(size_t)i * 2], b = in[(size_t)i * 2 + 1];
  int w0 = __builtin_amdgcn_cvt_pk_fp8_f32(a.x * s, a.y * s, 0, false);
  w0 = __builtin_amdgcn_cvt_pk_fp8_f32(a.z * s, a.w * s, w0, true);
  int w1 = __builtin_amdgcn_cvt_pk_fp8_f32(b.x * s, b.y * s, 0, false);
  w1 = __builtin_amdgcn_cvt_pk_fp8_f32(b.z * s, b.w * s, w1, true);
  out[i] = make_uint2((unsigned)w0, (unsigned)w1);
}

// ---------- W1 fp32 [128][128] -> bf16 transposed W1t[c][k] ----------
__global__ void k_cvtW(const float* __restrict__ W, unsigned int* __restrict__ Wt) {
  int i = blockIdx.x * 256 + threadIdx.x;  // 0..8191
  int c = i >> 6, kp = i & 63;
  float w0 = W[(size_t)(2 * kp) * 128 + c];
  float w1 = W[(size_t)(2 * kp + 1) * 128 + c];
  Wt[c * 64 + kp] = packbf(w0, w1);
}

// ---------- fp8 gather-aggregate core: acc = self + sum_src rows ----------
__device__ __forceinline__ void accf8(float* a, uint2 v) {
  float2v f;
  f = __builtin_amdgcn_cvt_pk_f32_fp8((int)v.x, false); a[0] += f.x; a[1] += f.y;
  f = __builtin_amdgcn_cvt_pk_f32_fp8((int)v.x, true);  a[2] += f.x; a[3] += f.y;
  f = __builtin_amdgcn_cvt_pk_f32_fp8((int)v.y, false); a[4] += f.x; a[5] += f.y;
  f = __builtin_amdgcn_cvt_pk_f32_fp8((int)v.y, true);  a[6] += f.x; a[7] += f.y;
}

#define AGG_CORE8(IN, NODE, L, A)                                                \
  float A[8] = {0.f, 0.f, 0.f, 0.f, 0.f, 0.f, 0.f, 0.f};                         \
  {                                                                              \
    uint2 sv = IN[(size_t)(NODE)*16 + (L)];                                      \
    accf8(A, sv);                                                                \
  }                                                                              \
  {                                                                              \
    int i = rowstart[NODE], end = rowstart[(NODE) + 1];                          \
    for (; i + 7 < end; i += 8) {                                                \
      int s0 = csr[i], s1 = csr[i + 1], s2 = csr[i + 2], s3 = csr[i + 3];        \
      int s4 = csr[i + 4], s5 = csr[i + 5], s6 = csr[i + 6], s7 = csr[i + 7];    \
      uint2 v0 = IN[(size_t)s0 * 16 + (L)];                                      \
      uint2 v1 = IN[(size_t)s1 * 16 + (L)];                                      \
      uint2 v2 = IN[(size_t)s2 * 16 + (L)];                                      \
      uint2 v3 = IN[(size_t)s3 * 16 + (L)];                                      \
      uint2 v4 = IN[(size_t)s4 * 16 + (L)];                                      \
      uint2 v5 = IN[(size_t)s5 * 16 + (L)];                                      \
      uint2 v6 = IN[(size_t)s6 * 16 + (L)];                                      \
      uint2 v7 = IN[(size_t)s7 * 16 + (L)];                                      \
      accf8(A, v0); accf8(A, v1); accf8(A, v2); accf8(A, v3);                    \
      accf8(A, v4); accf8(A, v5); accf8(A, v6); accf8(A, v7);                    \
    }                                                                            \
    for (; i + 3 < end; i += 4) {                                                \
      int s0 = csr[i], s1 = csr[i + 1], s2 = csr[i + 2], s3 = csr[i + 3];        \
      uint2 v0 = IN[(size_t)s0 * 16 + (L)];                                      \
      uint2 v1 = IN[(size_t)s1 * 16 + (L)];                                      \
      uint2 v2 = IN[(size_t)s2 * 16 + (L)];                                      \
      uint2 v3 = IN[(size_t)s3 * 16 + (L)];                                      \
      accf8(A, v0); accf8(A, v1); accf8(A, v2); accf8(A, v3);                    \
    }                                                                            \
    for (; i < end; ++i) {                                                       \
      uint2 v0 = IN[(size_t)csr[i] * 16 + (L)];                                  \
      accf8(A, v0);                                                              \
    }                                                                            \
  }

// ---------- fused agg1 + GEMM1 (MFMA): h1s8[v] = fp8(16*dinv*relu(Agg(x)@W1+b1)) ----------
// Block = 16 nodes (degree-sorted) = one 16x128 A-tile. 4 waves x 2 col-tiles MFMA.
// Input xs8 = fp8(8*dinv*x) -> acc*(dinv/8) = Agg(x) row (true scale).
__global__ __launch_bounds__(256) void k_agg1g(const uint2* __restrict__ in,
                                               const unsigned int* __restrict__ W1t,
                                               const float* __restrict__ bias,
                                               uint2* __restrict__ out,
                                               const int* __restrict__ rowstart,
                                               const int* __restrict__ csr,
                                               const float* __restrict__ dinv,
                                               const int* __restrict__ order) {
  __shared__ uint4 At[16 * 16];   // bf16 A-tile, row r chunk s at At[r*16 + (s^(r&7))]
  __shared__ float Ot[16 * 128];  // f32 out-tile, elem (r,c) at byte r*512 + ((c*4)^((r&7)<<4))
  __shared__ float sdv[16];
  int tid = threadIdx.x;
  int qw = tid >> 4, l = tid & 15;
  int pos = blockIdx.x * 16 + qw;
  int node = order[pos];
  AGG_CORE8(in, node, l, a)
  float dv = dinv[node];
  if (l == 0) sdv[qw] = dv;
  {
    float ds = dv * 0.125f;  // undo the 8x input prescale
    uint4 o;
    o.x = packbf(a[0] * ds, a[1] * ds); o.y = packbf(a[2] * ds, a[3] * ds);
    o.z = packbf(a[4] * ds, a[5] * ds); o.w = packbf(a[6] * ds, a[7] * ds);
    At[qw * 16 + (l ^ (qw & 7))] = o;
  }
  __syncthreads();

  // MFMA: wave w covers col-tiles {2w, 2w+1}
  int w = tid >> 6, lane = tid & 63;
  int m = lane & 15, g = lane >> 4;
  float4v acc[2];
  acc[0] = (float4v)0.f;
  acc[1] = (float4v)0.f;
#pragma unroll
  for (int ks = 0; ks < 4; ++ks) {
    int slot = ks * 4 + g;
    short8v af = *(const short8v*)&At[m * 16 + (slot ^ (m & 7))];
#pragma unroll
    for (int t = 0; t < 2; ++t) {
      int c = (w * 2 + t) * 16 + m;
      short8v bf = *(const short8v*)&W1t[c * 64 + ks * 16 + g * 4];
      acc[t] = __builtin_amdgcn_mfma_f32_16x16x32_bf16(af, bf, acc[t], 0, 0, 0);
    }
  }
  // epilogue: bias + relu + (16*dinv) prescale -> swizzled f32 tile
#pragma unroll
  for (int t = 0; t < 2; ++t) {
    int c = (w * 2 + t) * 16 + m;
    float bl = bias[c];
#pragma unroll
    for (int j = 0; j < 4; ++j) {
      int r = g * 4 + j;
      float v = fmaxf(acc[t][j] + bl, 0.f) * (sdv[r] * 16.f);
      *(float*)((char*)Ot + r * 512 + ((c * 4) ^ ((r & 7) << 4))) = v;
    }
  }
  __syncthreads();
  // readout: quarter-wave qw streams row qw, packs fp8
  {
    int s = (qw & 7) << 4;
    const char* base = (const char*)Ot + qw * 512;
    float4 f0 = *(const float4*)(base + ((l * 32) ^ s));
    float4 f1 = *(const float4*)(base + ((l * 32 + 16) ^ s));
    int w0 = __builtin_amdgcn_cvt_pk_fp8_f32(f0.x, f0.y, 0, false);
    w0 = __builtin_amdgcn_cvt_pk_fp8_f32(f0.z, f0.w, w0, true);
    int w1 = __builtin_amdgcn_cvt_pk_fp8_f32(f1.x, f1.y, 0, false);
    w1 = __builtin_amdgcn_cvt_pk_fp8_f32(f1.z, f1.w, w1, true);
    out[(size_t)node * 16 + l] = make_uint2((unsigned)w0, (unsigned)w1);
  }
}

// agg2 + fused per-graph sum pool. Input h1s8 = fp8(16*h1s_true); poolsum = 16*true sums.
__global__ __launch_bounds__(256) void k_agg2p(const uint2* __restrict__ in,
                                               float* __restrict__ poolsum,
                                               const int* __restrict__ rowstart,
                                               const int* __restrict__ csr,
                                               const float* __restrict__ dinv,
                                               const int* __restrict__ order) {
  __shared__ float sh[16][128];
  int nl = threadIdx.x >> 4, l = threadIdx.x & 15;
  int pos = blockIdx.x * 16 + nl;
  int node = order[pos];
  AGG_CORE8(in, node, l, a)
  float dv = dinv[node];
#pragma unroll
  for (int j = 0; j < 8; ++j) a[j] *= dv;
  *(float4*)&sh[nl][l * 8] = make_float4(a[0], a[1], a[2], a[3]);
  *(float4*)&sh[nl][l * 8 + 4] = make_float4(a[4], a[5], a[6], a[7]);
  __syncthreads();
  int tid = threadIdx.x;
  if (tid < 128) {
    int n0 = blockIdx.x * 16;
    int gA = n0 / NPG;
    int split = (gA + 1) * NPG - n0;  // positions [0,split) belong to gA
    if (split > 16) split = 16;
    float sA = 0.f, sB = 0.f;
#pragma unroll
    for (int n = 0; n < 16; ++n) {
      float v = sh[n][tid];
      if (n < split) sA += v; else sB += v;
    }
    atomicAdd(&poolsum[gA * 128 + tid], sA);
    if (split < 16) atomicAdd(&poolsum[(gA + 1) * 128 + tid], sB);
  }
}

// ---------- GEMM2 small-M: out[M x 128] = (A*ascale) @ W + bias, 8 rows/block ----------
__global__ __launch_bounds__(256) void k_gemm2s(const float* __restrict__ A,
                                                const float* __restrict__ W,
                                                const float* __restrict__ bias,
                                                float* __restrict__ out, int M, float ascale) {
  __shared__ float As[8][128];
  int tid = threadIdx.x;
  int row0 = blockIdx.x * 8;
  {
    int r = tid >> 5, c4 = (tid & 31) * 4;
    float4 v = make_float4(0.f, 0.f, 0.f, 0.f);
    if (row0 + r < M) v = *(const float4*)&A[(size_t)(row0 + r) * 128 + c4];
    *(float4*)&As[r][c4] = make_float4(v.x * ascale, v.y * ascale, v.z * ascale, v.w * ascale);
  }
  __syncthreads();
  int r = tid >> 5, c0 = (tid & 31) * 4;
  float acc0 = 0.f, acc1 = 0.f, acc2 = 0.f, acc3 = 0.f;
  for (int k = 0; k < 128; ++k) {
    float a = As[r][k];
    float4 wv = *(const float4*)&W[(size_t)k * 128 + c0];
    acc0 = fmaf(a, wv.x, acc0); acc1 = fmaf(a, wv.y, acc1);
    acc2 = fmaf(a, wv.z, acc2); acc3 = fmaf(a, wv.w, acc3);
  }
  if (row0 + r < M) {
    float4 o;
    o.x = acc0 + bias[c0]; o.y = acc1 + bias[c0 + 1];
    o.z = acc2 + bias[c0 + 2]; o.w = acc3 + bias[c0 + 3];
    *(float4*)&out[(size_t)(row0 + r) * 128 + c0] = o;
  }
}

extern "C" void kernel_launch(void* const* d_in, const int* in_sizes, int n_in,
                              void* d_out, int out_size, void* d_ws, size_t ws_size,
                              hipStream_t stream) {
  const float* x  = (const float*)d_in[0];
  const void* edges = d_in[1];
  const float* W1 = (const float*)d_in[3];
  const float* b1 = (const float*)d_in[4];
  const float* W2 = (const float*)d_in[5];
  const float* b2 = (const float*)d_in[6];
  float* out = (float*)d_out;

  // workspace layout (bytes), ~40.7 MB total
  char* ws = (char*)d_ws;
  float* poolsum  = (float*)(ws + 0);          // 256000  (zeroed)
  int*   hist     = (int*)(ws + 256000);       // 400384
  int*   histS    = (int*)(ws + 656384);       // 400384
  int*   bsums    = (int*)(ws + 1056768);      // 2048
  int*   rowstart = (int*)(ws + 1058816);      // 400016
  float* dinv     = (float*)(ws + 1458832);    // 400000
  int*   order    = (int*)(ws + 1858832);      // 400000
  unsigned int* W1t = (unsigned int*)(ws + 2258832);     // 32768 (bf16 W1^T)
  unsigned int* sorted = (unsigned int*)(ws + 2291600);  // 6.4 MB
  int*   csr      = (int*)(ws + 8691600);      // 6.4 MB
  void*  xs8      = (void*)(ws + 15091600);    // 12.8 MB  fp8(8*dinv*x)
  void*  h1s8     = (void*)(ws + 27891600);    // 12.8 MB  fp8(16*dinv*h1)

  hipMemsetAsync(poolsum, 0, 256000, stream);

  const int NH = NBK * NBLK;  // 100096 histogram entries

  k_hist1<<<NBLK, 256, 0, stream>>>(edges, hist);
  k_scan_block<<<(NH + 255) / 256, 256, 0, stream>>>(hist, histS, bsums, NH);
  k_scan_sums<<<1, 512, 0, stream>>>(bsums, (NH + 255) / 256);
  k_scan_add<<<(NH + 255) / 256, 256, 0, stream>>>(histS, bsums, NH);
  k_scatter<<<NBLK, 256, 0, stream>>>(edges, histS, sorted);
  k_passB2<<<NBK, 256, 0, stream>>>(sorted, histS, rowstart, dinv, csr);
  k_order<<<NG, 256, 0, stream>>>(rowstart, order);

  // xs8 = fp8(8*dinv*x); W1t = bf16(W1^T)
  k_cvt8<<<NN * HD / 8 / 256, 256, 0, stream>>>((const float4*)x, (uint2*)xs8, dinv);
  k_cvtW<<<32, 256, 0, stream>>>(W1, W1t);

  // conv1 fused: h1s8 = fp8( 16 * dinv * relu( Agg(x) @ W1 + b1 ) )
  k_agg1g<<<NN / 16, 256, 0, stream>>>((const uint2*)xs8, W1t, b1, (uint2*)h1s8,
                                       rowstart, csr, dinv, order);
  // conv2 fused with pool: poolsum = 16 * sum_graph( dinv*(h1s self+gather) )
  k_agg2p<<<NN / 16, 256, 0, stream>>>((const uint2*)h1s8, poolsum, rowstart, csr, dinv, order);
  // out = (poolsum/(200*16)) @ W2 + b2
  k_gemm2s<<<(NG + 7) / 8, 256, 0, stream>>>(poolsum, W2, b2, out, NG, 1.f / 3200.f);
}